// Round 1
// baseline (778.208 us; speedup 1.0000x reference)
//
#include <hip/hip_runtime.h>

// HiPPO-LegS scan x_t = A_t x_{t-1} + B_t * u_t  via chunked parallel scan.
// L=4096, B=256, N=64.  Subchunks of 16 (256), superchunks of 64 (64).
// K1: suffix products + w_t per subchunk (256 blocks, parallel)
// K1b: combine 4 subchunks -> superchunk product P_s, upgrade w_t (64 blocks)
// K1c: z_s[b] = sum_t inputs[t,b] * w_t  (small GEMM, 256 blocks)
// K2: sequential carry over 64 superchunks: h = P_s h + z_s, store H[s] (64 blocks)
// K3: recompute scan inside each superchunk from H[s], write outputs (256 blocks)

#define TID ((int)threadIdx.x)

constexpr int SUBL  = 16;
constexpr int PAD   = 68;   // LDS row pad: 16B-aligned float4 rows, bank stride 4

// ws layout (floats)
constexpr size_t WS_W = 0;                       // 4096*64        = 262144
constexpr size_t WS_Q = 262144;                  // 256*4096       = 1048576
constexpr size_t WS_P = WS_Q + 1048576;          // 64*4096        = 262144
constexpr size_t WS_Z = WS_P + 262144;           // 64*256*64      = 1048576
constexpr size_t WS_H = WS_Z + 1048576;          // 64*256*64      = 1048576

// stage 64x64 row-major global tile into LDS with pad-68 rows (float4)
__device__ __forceinline__ void stage64x64(const float* __restrict__ g, float* __restrict__ l) {
#pragma unroll
  for (int r = 0; r < 4; ++r) {
    int id = TID + 256 * r;
    int i = id >> 4, j0 = (id & 15) << 2;
    *reinterpret_cast<float4*>(&l[i * PAD + j0]) =
        *reinterpret_cast<const float4*>(&g[i * 64 + j0]);
  }
}

// Dl = Ml @ Al   (all LDS, pad-68 rows). Tiles: rows i = i_lo+16a, cols j = 4*i_hi+q.
// Dl must be distinct from Ml/Al (no internal barrier).
__device__ __forceinline__ void matmul_tile(const float* __restrict__ Ml,
                                            const float* __restrict__ Al,
                                            float* __restrict__ Dl,
                                            int i_lo, int i_hi) {
  float acc[4][4];
#pragma unroll
  for (int a = 0; a < 4; ++a)
#pragma unroll
    for (int b = 0; b < 4; ++b) acc[a][b] = 0.f;
  const int j0 = i_hi << 2;
#pragma unroll
  for (int kq = 0; kq < 16; ++kq) {
    const int k0 = kq << 2;
    float4 mf[4], af[4];
#pragma unroll
    for (int a = 0; a < 4; ++a)
      mf[a] = *reinterpret_cast<const float4*>(&Ml[(i_lo + 16 * a) * PAD + k0]);
#pragma unroll
    for (int kk = 0; kk < 4; ++kk)
      af[kk] = *reinterpret_cast<const float4*>(&Al[(k0 + kk) * PAD + j0]);
#pragma unroll
    for (int a = 0; a < 4; ++a) {
      acc[a][0] += mf[a].x * af[0].x + mf[a].y * af[1].x + mf[a].z * af[2].x + mf[a].w * af[3].x;
      acc[a][1] += mf[a].x * af[0].y + mf[a].y * af[1].y + mf[a].z * af[2].y + mf[a].w * af[3].y;
      acc[a][2] += mf[a].x * af[0].z + mf[a].y * af[1].z + mf[a].z * af[2].z + mf[a].w * af[3].z;
      acc[a][3] += mf[a].x * af[0].w + mf[a].y * af[1].w + mf[a].z * af[2].w + mf[a].w * af[3].w;
    }
  }
#pragma unroll
  for (int a = 0; a < 4; ++a)
    *reinterpret_cast<float4*>(&Dl[(i_lo + 16 * a) * PAD + j0]) =
        make_float4(acc[a][0], acc[a][1], acc[a][2], acc[a][3]);
}

// ---------------- K1: per-subchunk suffix products + w_t ----------------
__global__ __launch_bounds__(256) void k1_suffix(const float* __restrict__ Ag,
                                                 const float* __restrict__ Bg,
                                                 float* __restrict__ W,
                                                 float* __restrict__ Qw) {
  __shared__ float Ms[2][64 * PAD];
  __shared__ float As[64 * PAD];
  __shared__ float Bvs[64];
  const int c = blockIdx.x;
  const int i_lo = TID & 15, i_hi = TID >> 4;
  for (int idx = TID; idx < 64 * PAD; idx += 256) Ms[0][idx] = 0.f;
  __syncthreads();
  if (TID < 64) Ms[0][TID * PAD + TID] = 1.f;
  int cur = 0;
  for (int k = SUBL - 1; k >= 0; --k) {
    const int t = c * SUBL + k;
    stage64x64(Ag + (size_t)t * 4096, As);
    if (TID < 16)
      *reinterpret_cast<float4*>(&Bvs[TID * 4]) =
          *reinterpret_cast<const float4*>(&Bg[t * 64 + TID * 4]);
    __syncthreads();
    // w_t = Ms[cur] @ Bv   (Ms[cur] = A_{end}...A_{t+1})
    if (TID < 64) {
      float wv = 0.f;
#pragma unroll
      for (int kq = 0; kq < 16; ++kq) {
        float4 m = *reinterpret_cast<const float4*>(&Ms[cur][TID * PAD + kq * 4]);
        float4 b = *reinterpret_cast<const float4*>(&Bvs[kq * 4]);
        wv += m.x * b.x + m.y * b.y + m.z * b.z + m.w * b.w;
      }
      W[t * 64 + TID] = wv;
    }
    // Ms <- Ms @ A_t
    matmul_tile(Ms[cur], As, Ms[cur ^ 1], i_lo, i_hi);
    __syncthreads();
    cur ^= 1;
  }
  // Q[c] = Ms[cur]
#pragma unroll
  for (int r = 0; r < 4; ++r) {
    int id = TID + 256 * r;
    int i = id >> 4, j0 = (id & 15) << 2;
    *reinterpret_cast<float4*>(&Qw[(size_t)c * 4096 + i * 64 + j0]) =
        *reinterpret_cast<const float4*>(&Ms[cur][i * PAD + j0]);
  }
}

// ---------------- K1b: combine subchunks -> superchunk; upgrade w ----------------
__global__ __launch_bounds__(256) void k1b_combine(const float* __restrict__ Qw,
                                                   float* __restrict__ W,
                                                   float* __restrict__ Pw) {
  __shared__ float R[2][64 * PAD];
  __shared__ float Qs[64 * PAD];
  __shared__ float wm[16 * PAD];
  const int s = blockIdx.x;
  const int i_lo = TID & 15, i_hi = TID >> 4;
  int cur = 0;
  for (int m = 3; m >= 0; --m) {
    const int c = 4 * s + m;
    stage64x64(Qw + (size_t)c * 4096, Qs);
    {
      int tt = TID >> 4, i0 = (TID & 15) << 2;  // 16 t-rows x 16 float4
      *reinterpret_cast<float4*>(&wm[tt * PAD + i0]) =
          *reinterpret_cast<const float4*>(&W[(size_t)(c * 16 + tt) * 64 + i0]);
    }
    __syncthreads();
    if (m < 3) {
      // w'_t = R @ w_t  for this subchunk;  R = Q_{3}..Q_{m+1}
      float acc[4] = {0.f, 0.f, 0.f, 0.f};
#pragma unroll
      for (int kq = 0; kq < 16; ++kq) {
        const int k0 = kq << 2;
        float4 wf = *reinterpret_cast<const float4*>(&wm[i_hi * PAD + k0]);
#pragma unroll
        for (int a = 0; a < 4; ++a) {
          float4 rf = *reinterpret_cast<const float4*>(&R[cur][(i_lo + 16 * a) * PAD + k0]);
          acc[a] += rf.x * wf.x + rf.y * wf.y + rf.z * wf.z + rf.w * wf.w;
        }
      }
#pragma unroll
      for (int a = 0; a < 4; ++a)
        W[(size_t)(c * 16 + i_hi) * 64 + i_lo + 16 * a] = acc[a];
      matmul_tile(R[cur], Qs, R[cur ^ 1], i_lo, i_hi);
    } else {
      // R = Q_3
#pragma unroll
      for (int r = 0; r < 4; ++r) {
        int id = TID + 256 * r;
        int i = id >> 4, j0 = (id & 15) << 2;
        *reinterpret_cast<float4*>(&R[cur ^ 1][i * PAD + j0]) =
            *reinterpret_cast<const float4*>(&Qs[i * PAD + j0]);
      }
    }
    __syncthreads();
    cur ^= 1;
  }
  // P[s] = Q3 Q2 Q1 Q0
#pragma unroll
  for (int r = 0; r < 4; ++r) {
    int id = TID + 256 * r;
    int i = id >> 4, j0 = (id & 15) << 2;
    *reinterpret_cast<float4*>(&Pw[(size_t)s * 4096 + i * 64 + j0]) =
        *reinterpret_cast<const float4*>(&R[cur][i * PAD + j0]);
  }
}

// ---------------- K1c: z_s[b,i] = sum_t inputs[t,b]*w_t[i] ----------------
__global__ __launch_bounds__(256) void k1c_zgemm(const float* __restrict__ inp,
                                                 const float* __restrict__ W,
                                                 float* __restrict__ Zw) {
  __shared__ float inT[64 * PAD];  // [b_loc][t_loc]
  __shared__ float wm[64 * PAD];   // [t_loc][i]
  const int s = blockIdx.x >> 2, g = blockIdx.x & 3;
  const int b0 = 64 * g, t0 = s * 64;
  const int i_lo = TID & 15, i_hi = TID >> 4;
#pragma unroll
  for (int r = 0; r < 4; ++r) {
    int id = TID + 256 * r;
    int tl = id >> 4, b4 = (id & 15) << 2;
    float4 v = *reinterpret_cast<const float4*>(&inp[(size_t)(t0 + tl) * 256 + b0 + b4]);
    inT[(b4 + 0) * PAD + tl] = v.x;
    inT[(b4 + 1) * PAD + tl] = v.y;
    inT[(b4 + 2) * PAD + tl] = v.z;
    inT[(b4 + 3) * PAD + tl] = v.w;
  }
#pragma unroll
  for (int r = 0; r < 4; ++r) {
    int id = TID + 256 * r;
    int tl = id >> 4, i0 = (id & 15) << 2;
    *reinterpret_cast<float4*>(&wm[tl * PAD + i0]) =
        *reinterpret_cast<const float4*>(&W[(size_t)(t0 + tl) * 64 + i0]);
  }
  __syncthreads();
  // out[b = i_lo+16a][i = 4*i_hi+q] = sum_t inT[b][t]*wm[t][i]
  float acc[4][4];
#pragma unroll
  for (int a = 0; a < 4; ++a)
#pragma unroll
    for (int q = 0; q < 4; ++q) acc[a][q] = 0.f;
  const int j0c = i_hi << 2;
#pragma unroll
  for (int kq = 0; kq < 16; ++kq) {
    const int k0 = kq << 2;
    float4 bf[4], wf[4];
#pragma unroll
    for (int a = 0; a < 4; ++a)
      bf[a] = *reinterpret_cast<const float4*>(&inT[(i_lo + 16 * a) * PAD + k0]);
#pragma unroll
    for (int kk = 0; kk < 4; ++kk)
      wf[kk] = *reinterpret_cast<const float4*>(&wm[(k0 + kk) * PAD + j0c]);
#pragma unroll
    for (int a = 0; a < 4; ++a) {
      acc[a][0] += bf[a].x * wf[0].x + bf[a].y * wf[1].x + bf[a].z * wf[2].x + bf[a].w * wf[3].x;
      acc[a][1] += bf[a].x * wf[0].y + bf[a].y * wf[1].y + bf[a].z * wf[2].y + bf[a].w * wf[3].y;
      acc[a][2] += bf[a].x * wf[0].z + bf[a].y * wf[1].z + bf[a].z * wf[2].z + bf[a].w * wf[3].z;
      acc[a][3] += bf[a].x * wf[0].w + bf[a].y * wf[1].w + bf[a].z * wf[2].w + bf[a].w * wf[3].w;
    }
  }
  __syncthreads();
  // transpose through LDS (reuse wm) for coalesced f4 store
#pragma unroll
  for (int a = 0; a < 4; ++a)
    *reinterpret_cast<float4*>(&wm[(i_lo + 16 * a) * PAD + j0c]) =
        make_float4(acc[a][0], acc[a][1], acc[a][2], acc[a][3]);
  __syncthreads();
#pragma unroll
  for (int r = 0; r < 4; ++r) {
    int id = TID + 256 * r;
    int bl = id >> 4, i0 = (id & 15) << 2;
    *reinterpret_cast<float4*>(&Zw[(size_t)s * 16384 + (b0 + bl) * 64 + i0]) =
        *reinterpret_cast<const float4*>(&wm[bl * PAD + i0]);
  }
}

// ---------------- K2: sequential superchunk carry ----------------
__global__ __launch_bounds__(256) void k2_carry(const float* __restrict__ Pw,
                                                const float* __restrict__ Zw,
                                                float* __restrict__ Hw) {
  __shared__ float Pt[64 * PAD];  // Pt[j][i] = P[i][j]
  __shared__ float xb[4 * PAD];
  const int g = blockIdx.x;
  const int bl = TID >> 6, i = TID & 63;
  const int bg = 4 * g + bl;
  for (int idx = TID; idx < 4 * PAD; idx += 256) xb[idx] = 0.f;
#pragma unroll
  for (int r = 0; r < 4; ++r) {
    int id = TID + 256 * r;
    int ir = id >> 4, j0 = (id & 15) << 2;
    float4 v = *reinterpret_cast<const float4*>(&Pw[ir * 64 + j0]);
    Pt[(j0 + 0) * PAD + ir] = v.x;
    Pt[(j0 + 1) * PAD + ir] = v.y;
    Pt[(j0 + 2) * PAD + ir] = v.z;
    Pt[(j0 + 3) * PAD + ir] = v.w;
  }
  __syncthreads();
  float h = 0.f;
  for (int s = 0; s < 64; ++s) {
    Hw[(size_t)s * 16384 + bg * 64 + i] = h;  // state BEFORE superchunk s
    float acc = Zw[(size_t)s * 16384 + bg * 64 + i];
#pragma unroll
    for (int jq = 0; jq < 16; ++jq) {
      const int j0 = jq << 2;
      float4 xf = *reinterpret_cast<const float4*>(&xb[bl * PAD + j0]);
      acc += Pt[(j0 + 0) * PAD + i] * xf.x + Pt[(j0 + 1) * PAD + i] * xf.y +
             Pt[(j0 + 2) * PAD + i] * xf.z + Pt[(j0 + 3) * PAD + i] * xf.w;
    }
    h = acc;
    __syncthreads();
    xb[bl * PAD + i] = h;
    if (s < 63) {
#pragma unroll
      for (int r = 0; r < 4; ++r) {
        int id = TID + 256 * r;
        int ir = id >> 4, j0 = (id & 15) << 2;
        float4 v = *reinterpret_cast<const float4*>(&Pw[(size_t)(s + 1) * 4096 + ir * 64 + j0]);
        Pt[(j0 + 0) * PAD + ir] = v.x;
        Pt[(j0 + 1) * PAD + ir] = v.y;
        Pt[(j0 + 2) * PAD + ir] = v.z;
        Pt[(j0 + 3) * PAD + ir] = v.w;
      }
    }
    __syncthreads();
  }
}

// ---------------- K3: recompute scan inside superchunk, write outputs ----------------
__global__ __launch_bounds__(256) void k3_final(const float* __restrict__ Ag,
                                                const float* __restrict__ Bg,
                                                const float* __restrict__ inp,
                                                const float* __restrict__ Hw,
                                                float* __restrict__ out) {
  __shared__ float As[64 * PAD];
  __shared__ float xs[64 * PAD];  // x[b_loc][j]
  __shared__ float Bvs[64];
  __shared__ float ins[64];
  const int s = blockIdx.x >> 2, g = blockIdx.x & 3;
  const int b0 = 64 * g;
  const int i_lo = TID & 15, i_hi = TID >> 4;
#pragma unroll
  for (int r = 0; r < 4; ++r) {
    int id = TID + 256 * r;
    int bl = id >> 4, i0 = (id & 15) << 2;
    *reinterpret_cast<float4*>(&xs[bl * PAD + i0]) =
        *reinterpret_cast<const float4*>(&Hw[(size_t)s * 16384 + (b0 + bl) * 64 + i0]);
  }
  for (int k = 0; k < 64; ++k) {
    const int t = s * 64 + k;
    stage64x64(Ag + (size_t)t * 4096, As);
    if (TID < 16)
      *reinterpret_cast<float4*>(&Bvs[TID * 4]) =
          *reinterpret_cast<const float4*>(&Bg[t * 64 + TID * 4]);
    if (TID >= 64 && TID < 80) {
      int q = TID - 64;
      *reinterpret_cast<float4*>(&ins[q * 4]) =
          *reinterpret_cast<const float4*>(&inp[(size_t)t * 256 + b0 + q * 4]);
    }
    __syncthreads();
    // new_x[i = i_lo+16a][b = i_hi+16r] = sum_j A[i][j]*x[b][j] + inputs[t][b]*Bv[i]
    float acc[4][4];
#pragma unroll
    for (int a = 0; a < 4; ++a)
#pragma unroll
      for (int r = 0; r < 4; ++r) acc[a][r] = 0.f;
#pragma unroll
    for (int jq = 0; jq < 16; ++jq) {
      const int j0 = jq << 2;
      float4 af[4], xf[4];
#pragma unroll
      for (int a = 0; a < 4; ++a)
        af[a] = *reinterpret_cast<const float4*>(&As[(i_lo + 16 * a) * PAD + j0]);
#pragma unroll
      for (int r = 0; r < 4; ++r)
        xf[r] = *reinterpret_cast<const float4*>(&xs[(i_hi + 16 * r) * PAD + j0]);
#pragma unroll
      for (int a = 0; a < 4; ++a)
#pragma unroll
        for (int r = 0; r < 4; ++r)
          acc[a][r] += af[a].x * xf[r].x + af[a].y * xf[r].y + af[a].z * xf[r].z + af[a].w * xf[r].w;
    }
    float bv[4], ui[4];
#pragma unroll
    for (int a = 0; a < 4; ++a) bv[a] = Bvs[i_lo + 16 * a];
#pragma unroll
    for (int r = 0; r < 4; ++r) ui[r] = ins[i_hi + 16 * r];
#pragma unroll
    for (int a = 0; a < 4; ++a)
#pragma unroll
      for (int r = 0; r < 4; ++r) acc[a][r] += bv[a] * ui[r];
    __syncthreads();  // all xs reads done before overwrite
#pragma unroll
    for (int r = 0; r < 4; ++r)
#pragma unroll
      for (int a = 0; a < 4; ++a)
        xs[(i_hi + 16 * r) * PAD + i_lo + 16 * a] = acc[a][r];
    __syncthreads();
    // coalesced f4 store of x_t
#pragma unroll
    for (int r = 0; r < 4; ++r) {
      int id = TID + 256 * r;
      int bl = id >> 4, i0 = (id & 15) << 2;
      *reinterpret_cast<float4*>(&out[((size_t)t * 256 + b0 + bl) * 64 + i0]) =
          *reinterpret_cast<const float4*>(&xs[bl * PAD + i0]);
    }
  }
}

extern "C" void kernel_launch(void* const* d_in, const int* in_sizes, int n_in,
                              void* d_out, int out_size, void* d_ws, size_t ws_size,
                              hipStream_t stream) {
  const float* inputs = (const float*)d_in[0];  // (4096, 256)
  const float* Ag     = (const float*)d_in[1];  // (4096, 64, 64)
  const float* Bg     = (const float*)d_in[2];  // (4096, 64)
  float* out = (float*)d_out;                   // (4096, 256, 64)
  float* ws  = (float*)d_ws;
  float* W  = ws + WS_W;
  float* Qw = ws + WS_Q;
  float* Pw = ws + WS_P;
  float* Zw = ws + WS_Z;
  float* Hw = ws + WS_H;

  k1_suffix<<<256, 256, 0, stream>>>(Ag, Bg, W, Qw);
  k1b_combine<<<64, 256, 0, stream>>>(Qw, W, Pw);
  k1c_zgemm<<<256, 256, 0, stream>>>(inputs, W, Zw);
  k2_carry<<<64, 256, 0, stream>>>(Pw, Zw, Hw);
  k3_final<<<256, 256, 0, stream>>>(Ag, Bg, inputs, Hw, out);
}

// Round 2
// 646.113 us; speedup vs baseline: 1.2044x; 1.2044x over previous
//
#include <hip/hip_runtime.h>
#include <cstdint>

// HiPPO-LegS scan x_t = A_t x_{t-1} + B_t * u_t  via chunked parallel scan.
// L=4096, B=256, N=64.  Subchunks of 16 (256), superchunks of 64 (64).
// K0: split A into fp16 hi/lo per-step slots (+Bv,u) for MFMA staging
// K1: suffix products + w_t per subchunk (256 blocks, fp32)
// K1b: combine 4 subchunks -> superchunk product P_s, upgrade w_t (64 blocks)
// K1c: z_s[b] = sum_t inputs[t,b] * w_t  (small GEMM, 256 blocks)
// K2: sequential carry over 64 superchunks: h = P_s h + z_s, store H[s] (64 blocks)
// K3 (MFMA): recompute scan inside each superchunk from H[s] with fp16 hi/lo
//            3-product MFMA (precision ~2^-21), double-buffered global_load_lds

#define TID ((int)threadIdx.x)

typedef _Float16 half8 __attribute__((ext_vector_type(8)));
typedef _Float16 half4v __attribute__((ext_vector_type(4)));
typedef float f32x4 __attribute__((ext_vector_type(4)));

constexpr int SUBL  = 16;
constexpr int PAD   = 68;   // fp32 LDS row pad (old kernels)

// old ws layout (floats)
constexpr size_t WS_W = 0;                       // 4096*64
constexpr size_t WS_Q = 262144;                  // 256*4096
constexpr size_t WS_P = WS_Q + 1048576;          // 64*4096
constexpr size_t WS_Z = WS_P + 262144;           // 64*256*64
constexpr size_t WS_H = WS_Z + 1048576;          // 64*256*64
constexpr size_t OLD_WS_FLOATS = WS_H + 1048576;

// A-slot layout for MFMA path (bytes per step t)
constexpr int SLOT   = 20480;   // 20 KB: 5 x (256 lanes x 16 B) staging chunks
constexpr int APITCH = 144;     // 72 fp16 per row (4-bank shift -> <=2-way conflicts)
constexpr int AL_OFF = 9216;    // Al array
constexpr int BV_OFF = 18432;   // Bv f32[64]
constexpr int U_OFF  = 18688;   // inputs row f32[256]
constexpr size_t AWS_BYTES = (size_t)4096 * SLOT;

// ---------------- shared helpers (fp32 path) ----------------
__device__ __forceinline__ void stage64x64(const float* __restrict__ g, float* __restrict__ l) {
#pragma unroll
  for (int r = 0; r < 4; ++r) {
    int id = TID + 256 * r;
    int i = id >> 4, j0 = (id & 15) << 2;
    *reinterpret_cast<float4*>(&l[i * PAD + j0]) =
        *reinterpret_cast<const float4*>(&g[i * 64 + j0]);
  }
}

__device__ __forceinline__ void matmul_tile(const float* __restrict__ Ml,
                                            const float* __restrict__ Al,
                                            float* __restrict__ Dl,
                                            int i_lo, int i_hi) {
  float acc[4][4];
#pragma unroll
  for (int a = 0; a < 4; ++a)
#pragma unroll
    for (int b = 0; b < 4; ++b) acc[a][b] = 0.f;
  const int j0 = i_hi << 2;
#pragma unroll
  for (int kq = 0; kq < 16; ++kq) {
    const int k0 = kq << 2;
    float4 mf[4], af[4];
#pragma unroll
    for (int a = 0; a < 4; ++a)
      mf[a] = *reinterpret_cast<const float4*>(&Ml[(i_lo + 16 * a) * PAD + k0]);
#pragma unroll
    for (int kk = 0; kk < 4; ++kk)
      af[kk] = *reinterpret_cast<const float4*>(&Al[(k0 + kk) * PAD + j0]);
#pragma unroll
    for (int a = 0; a < 4; ++a) {
      acc[a][0] += mf[a].x * af[0].x + mf[a].y * af[1].x + mf[a].z * af[2].x + mf[a].w * af[3].x;
      acc[a][1] += mf[a].x * af[0].y + mf[a].y * af[1].y + mf[a].z * af[2].y + mf[a].w * af[3].y;
      acc[a][2] += mf[a].x * af[0].z + mf[a].y * af[1].z + mf[a].z * af[2].z + mf[a].w * af[3].z;
      acc[a][3] += mf[a].x * af[0].w + mf[a].y * af[1].w + mf[a].z * af[2].w + mf[a].w * af[3].w;
    }
  }
#pragma unroll
  for (int a = 0; a < 4; ++a)
    *reinterpret_cast<float4*>(&Dl[(i_lo + 16 * a) * PAD + j0]) =
        make_float4(acc[a][0], acc[a][1], acc[a][2], acc[a][3]);
}

// ---------------- K0: split A -> fp16 hi/lo slots ----------------
__global__ __launch_bounds__(256) void k0_prep(const float* __restrict__ Ag,
                                               const float* __restrict__ Bg,
                                               const float* __restrict__ inp,
                                               unsigned char* __restrict__ Aws) {
  const int t = blockIdx.x;
  unsigned char* slot = Aws + (size_t)t * SLOT;
  const int i = TID >> 2, jq = TID & 3, j0 = jq << 4;
  const float* arow = Ag + (size_t)t * 4096 + i * 64 + j0;
  half8 hv[2], lv[2];
#pragma unroll
  for (int hf = 0; hf < 2; ++hf) {
#pragma unroll
    for (int r = 0; r < 2; ++r) {
      float4 v = *reinterpret_cast<const float4*>(arow + hf * 8 + r * 4);
      float vv[4] = {v.x, v.y, v.z, v.w};
#pragma unroll
      for (int e = 0; e < 4; ++e) {
        _Float16 h = (_Float16)vv[e];
        hv[hf][r * 4 + e] = h;
        lv[hf][r * 4 + e] = (_Float16)(vv[e] - (float)h);
      }
    }
  }
  *reinterpret_cast<half8*>(slot + i * APITCH + j0 * 2)           = hv[0];
  *reinterpret_cast<half8*>(slot + i * APITCH + j0 * 2 + 16)      = hv[1];
  *reinterpret_cast<half8*>(slot + AL_OFF + i * APITCH + j0 * 2)      = lv[0];
  *reinterpret_cast<half8*>(slot + AL_OFF + i * APITCH + j0 * 2 + 16) = lv[1];
  if (jq == 3) {  // zero row pad (cols 64..71)
    half8 z = {};
    *reinterpret_cast<half8*>(slot + i * APITCH + 128) = z;
    *reinterpret_cast<half8*>(slot + AL_OFF + i * APITCH + 128) = z;
  }
  if (TID < 16)
    *reinterpret_cast<float4*>(slot + BV_OFF + TID * 16) =
        *reinterpret_cast<const float4*>(Bg + (size_t)t * 64 + TID * 4);
  if (TID >= 64 && TID < 128) {
    int q = TID - 64;
    *reinterpret_cast<float4*>(slot + U_OFF + q * 16) =
        *reinterpret_cast<const float4*>(inp + (size_t)t * 256 + q * 4);
  }
}

// ---------------- K1: per-subchunk suffix products + w_t (fp32) ----------------
__global__ __launch_bounds__(256) void k1_suffix(const float* __restrict__ Ag,
                                                 const float* __restrict__ Bg,
                                                 float* __restrict__ W,
                                                 float* __restrict__ Qw) {
  __shared__ float Ms[2][64 * PAD];
  __shared__ float As[64 * PAD];
  __shared__ float Bvs[64];
  const int c = blockIdx.x;
  const int i_lo = TID & 15, i_hi = TID >> 4;
  for (int idx = TID; idx < 64 * PAD; idx += 256) Ms[0][idx] = 0.f;
  __syncthreads();
  if (TID < 64) Ms[0][TID * PAD + TID] = 1.f;
  int cur = 0;
  for (int k = SUBL - 1; k >= 0; --k) {
    const int t = c * SUBL + k;
    stage64x64(Ag + (size_t)t * 4096, As);
    if (TID < 16)
      *reinterpret_cast<float4*>(&Bvs[TID * 4]) =
          *reinterpret_cast<const float4*>(&Bg[t * 64 + TID * 4]);
    __syncthreads();
    if (TID < 64) {
      float wv = 0.f;
#pragma unroll
      for (int kq = 0; kq < 16; ++kq) {
        float4 m = *reinterpret_cast<const float4*>(&Ms[cur][TID * PAD + kq * 4]);
        float4 b = *reinterpret_cast<const float4*>(&Bvs[kq * 4]);
        wv += m.x * b.x + m.y * b.y + m.z * b.z + m.w * b.w;
      }
      W[t * 64 + TID] = wv;
    }
    matmul_tile(Ms[cur], As, Ms[cur ^ 1], i_lo, i_hi);
    __syncthreads();
    cur ^= 1;
  }
#pragma unroll
  for (int r = 0; r < 4; ++r) {
    int id = TID + 256 * r;
    int i = id >> 4, j0 = (id & 15) << 2;
    *reinterpret_cast<float4*>(&Qw[(size_t)c * 4096 + i * 64 + j0]) =
        *reinterpret_cast<const float4*>(&Ms[cur][i * PAD + j0]);
  }
}

// ---------------- K1b: combine subchunks -> superchunk; upgrade w ----------------
__global__ __launch_bounds__(256) void k1b_combine(const float* __restrict__ Qw,
                                                   float* __restrict__ W,
                                                   float* __restrict__ Pw) {
  __shared__ float R[2][64 * PAD];
  __shared__ float Qs[64 * PAD];
  __shared__ float wm[16 * PAD];
  const int s = blockIdx.x;
  const int i_lo = TID & 15, i_hi = TID >> 4;
  int cur = 0;
  for (int m = 3; m >= 0; --m) {
    const int c = 4 * s + m;
    stage64x64(Qw + (size_t)c * 4096, Qs);
    {
      int tt = TID >> 4, i0 = (TID & 15) << 2;
      *reinterpret_cast<float4*>(&wm[tt * PAD + i0]) =
          *reinterpret_cast<const float4*>(&W[(size_t)(c * 16 + tt) * 64 + i0]);
    }
    __syncthreads();
    if (m < 3) {
      float acc[4] = {0.f, 0.f, 0.f, 0.f};
#pragma unroll
      for (int kq = 0; kq < 16; ++kq) {
        const int k0 = kq << 2;
        float4 wf = *reinterpret_cast<const float4*>(&wm[i_hi * PAD + k0]);
#pragma unroll
        for (int a = 0; a < 4; ++a) {
          float4 rf = *reinterpret_cast<const float4*>(&R[cur][(i_lo + 16 * a) * PAD + k0]);
          acc[a] += rf.x * wf.x + rf.y * wf.y + rf.z * wf.z + rf.w * wf.w;
        }
      }
#pragma unroll
      for (int a = 0; a < 4; ++a)
        W[(size_t)(c * 16 + i_hi) * 64 + i_lo + 16 * a] = acc[a];
      matmul_tile(R[cur], Qs, R[cur ^ 1], i_lo, i_hi);
    } else {
#pragma unroll
      for (int r = 0; r < 4; ++r) {
        int id = TID + 256 * r;
        int i = id >> 4, j0 = (id & 15) << 2;
        *reinterpret_cast<float4*>(&R[cur ^ 1][i * PAD + j0]) =
            *reinterpret_cast<const float4*>(&Qs[i * PAD + j0]);
      }
    }
    __syncthreads();
    cur ^= 1;
  }
#pragma unroll
  for (int r = 0; r < 4; ++r) {
    int id = TID + 256 * r;
    int i = id >> 4, j0 = (id & 15) << 2;
    *reinterpret_cast<float4*>(&Pw[(size_t)s * 4096 + i * 64 + j0]) =
        *reinterpret_cast<const float4*>(&R[cur][i * PAD + j0]);
  }
}

// ---------------- K1c: z_s[b,i] = sum_t inputs[t,b]*w_t[i] ----------------
__global__ __launch_bounds__(256) void k1c_zgemm(const float* __restrict__ inp,
                                                 const float* __restrict__ W,
                                                 float* __restrict__ Zw) {
  __shared__ float inT[64 * PAD];
  __shared__ float wm[64 * PAD];
  const int s = blockIdx.x >> 2, g = blockIdx.x & 3;
  const int b0 = 64 * g, t0 = s * 64;
  const int i_lo = TID & 15, i_hi = TID >> 4;
#pragma unroll
  for (int r = 0; r < 4; ++r) {
    int id = TID + 256 * r;
    int tl = id >> 4, b4 = (id & 15) << 2;
    float4 v = *reinterpret_cast<const float4*>(&inp[(size_t)(t0 + tl) * 256 + b0 + b4]);
    inT[(b4 + 0) * PAD + tl] = v.x;
    inT[(b4 + 1) * PAD + tl] = v.y;
    inT[(b4 + 2) * PAD + tl] = v.z;
    inT[(b4 + 3) * PAD + tl] = v.w;
  }
#pragma unroll
  for (int r = 0; r < 4; ++r) {
    int id = TID + 256 * r;
    int tl = id >> 4, i0 = (id & 15) << 2;
    *reinterpret_cast<float4*>(&wm[tl * PAD + i0]) =
        *reinterpret_cast<const float4*>(&W[(size_t)(t0 + tl) * 64 + i0]);
  }
  __syncthreads();
  float acc[4][4];
#pragma unroll
  for (int a = 0; a < 4; ++a)
#pragma unroll
    for (int q = 0; q < 4; ++q) acc[a][q] = 0.f;
  const int j0c = i_hi << 2;
#pragma unroll
  for (int kq = 0; kq < 16; ++kq) {
    const int k0 = kq << 2;
    float4 bf[4], wf[4];
#pragma unroll
    for (int a = 0; a < 4; ++a)
      bf[a] = *reinterpret_cast<const float4*>(&inT[(i_lo + 16 * a) * PAD + k0]);
#pragma unroll
    for (int kk = 0; kk < 4; ++kk)
      wf[kk] = *reinterpret_cast<const float4*>(&wm[(k0 + kk) * PAD + j0c]);
#pragma unroll
    for (int a = 0; a < 4; ++a) {
      acc[a][0] += bf[a].x * wf[0].x + bf[a].y * wf[1].x + bf[a].z * wf[2].x + bf[a].w * wf[3].x;
      acc[a][1] += bf[a].x * wf[0].y + bf[a].y * wf[1].y + bf[a].z * wf[2].y + bf[a].w * wf[3].y;
      acc[a][2] += bf[a].x * wf[0].z + bf[a].y * wf[1].z + bf[a].z * wf[2].z + bf[a].w * wf[3].z;
      acc[a][3] += bf[a].x * wf[0].w + bf[a].y * wf[1].w + bf[a].z * wf[2].w + bf[a].w * wf[3].w;
    }
  }
  __syncthreads();
#pragma unroll
  for (int a = 0; a < 4; ++a)
    *reinterpret_cast<float4*>(&wm[(i_lo + 16 * a) * PAD + j0c]) =
        make_float4(acc[a][0], acc[a][1], acc[a][2], acc[a][3]);
  __syncthreads();
#pragma unroll
  for (int r = 0; r < 4; ++r) {
    int id = TID + 256 * r;
    int bl = id >> 4, i0 = (id & 15) << 2;
    *reinterpret_cast<float4*>(&Zw[(size_t)s * 16384 + (b0 + bl) * 64 + i0]) =
        *reinterpret_cast<const float4*>(&wm[bl * PAD + i0]);
  }
}

// ---------------- K2: sequential superchunk carry ----------------
__global__ __launch_bounds__(256) void k2_carry(const float* __restrict__ Pw,
                                                const float* __restrict__ Zw,
                                                float* __restrict__ Hw) {
  __shared__ float Pt[64 * PAD];
  __shared__ float xb[4 * PAD];
  const int g = blockIdx.x;
  const int bl = TID >> 6, i = TID & 63;
  const int bg = 4 * g + bl;
  for (int idx = TID; idx < 4 * PAD; idx += 256) xb[idx] = 0.f;
#pragma unroll
  for (int r = 0; r < 4; ++r) {
    int id = TID + 256 * r;
    int ir = id >> 4, j0 = (id & 15) << 2;
    float4 v = *reinterpret_cast<const float4*>(&Pw[ir * 64 + j0]);
    Pt[(j0 + 0) * PAD + ir] = v.x;
    Pt[(j0 + 1) * PAD + ir] = v.y;
    Pt[(j0 + 2) * PAD + ir] = v.z;
    Pt[(j0 + 3) * PAD + ir] = v.w;
  }
  __syncthreads();
  float h = 0.f;
  for (int s = 0; s < 64; ++s) {
    Hw[(size_t)s * 16384 + bg * 64 + i] = h;
    float acc = Zw[(size_t)s * 16384 + bg * 64 + i];
#pragma unroll
    for (int jq = 0; jq < 16; ++jq) {
      const int j0 = jq << 2;
      float4 xf = *reinterpret_cast<const float4*>(&xb[bl * PAD + j0]);
      acc += Pt[(j0 + 0) * PAD + i] * xf.x + Pt[(j0 + 1) * PAD + i] * xf.y +
             Pt[(j0 + 2) * PAD + i] * xf.z + Pt[(j0 + 3) * PAD + i] * xf.w;
    }
    h = acc;
    __syncthreads();
    xb[bl * PAD + i] = h;
    if (s < 63) {
#pragma unroll
      for (int r = 0; r < 4; ++r) {
        int id = TID + 256 * r;
        int ir = id >> 4, j0 = (id & 15) << 2;
        float4 v = *reinterpret_cast<const float4*>(&Pw[(size_t)(s + 1) * 4096 + ir * 64 + j0]);
        Pt[(j0 + 0) * PAD + ir] = v.x;
        Pt[(j0 + 1) * PAD + ir] = v.y;
        Pt[(j0 + 2) * PAD + ir] = v.z;
        Pt[(j0 + 3) * PAD + ir] = v.w;
      }
    }
    __syncthreads();
  }
}

// ---------------- K3 (fp32 fallback) ----------------
__global__ __launch_bounds__(256) void k3_final(const float* __restrict__ Ag,
                                                const float* __restrict__ Bg,
                                                const float* __restrict__ inp,
                                                const float* __restrict__ Hw,
                                                float* __restrict__ out) {
  __shared__ float As[64 * PAD];
  __shared__ float xs[64 * PAD];
  __shared__ float Bvs[64];
  __shared__ float ins[64];
  const int s = blockIdx.x >> 2, g = blockIdx.x & 3;
  const int b0 = 64 * g;
  const int i_lo = TID & 15, i_hi = TID >> 4;
#pragma unroll
  for (int r = 0; r < 4; ++r) {
    int id = TID + 256 * r;
    int bl = id >> 4, i0 = (id & 15) << 2;
    *reinterpret_cast<float4*>(&xs[bl * PAD + i0]) =
        *reinterpret_cast<const float4*>(&Hw[(size_t)s * 16384 + (b0 + bl) * 64 + i0]);
  }
  for (int k = 0; k < 64; ++k) {
    const int t = s * 64 + k;
    stage64x64(Ag + (size_t)t * 4096, As);
    if (TID < 16)
      *reinterpret_cast<float4*>(&Bvs[TID * 4]) =
          *reinterpret_cast<const float4*>(&Bg[t * 64 + TID * 4]);
    if (TID >= 64 && TID < 80) {
      int q = TID - 64;
      *reinterpret_cast<float4*>(&ins[q * 4]) =
          *reinterpret_cast<const float4*>(&inp[(size_t)t * 256 + b0 + q * 4]);
    }
    __syncthreads();
    float acc[4][4];
#pragma unroll
    for (int a = 0; a < 4; ++a)
#pragma unroll
      for (int r = 0; r < 4; ++r) acc[a][r] = 0.f;
#pragma unroll
    for (int jq = 0; jq < 16; ++jq) {
      const int j0 = jq << 2;
      float4 af[4], xf[4];
#pragma unroll
      for (int a = 0; a < 4; ++a)
        af[a] = *reinterpret_cast<const float4*>(&As[(i_lo + 16 * a) * PAD + j0]);
#pragma unroll
      for (int r = 0; r < 4; ++r)
        xf[r] = *reinterpret_cast<const float4*>(&xs[(i_hi + 16 * r) * PAD + j0]);
#pragma unroll
      for (int a = 0; a < 4; ++a)
#pragma unroll
        for (int r = 0; r < 4; ++r)
          acc[a][r] += af[a].x * xf[r].x + af[a].y * xf[r].y + af[a].z * xf[r].z + af[a].w * xf[r].w;
    }
    float bv[4], ui[4];
#pragma unroll
    for (int a = 0; a < 4; ++a) bv[a] = Bvs[i_lo + 16 * a];
#pragma unroll
    for (int r = 0; r < 4; ++r) ui[r] = ins[i_hi + 16 * r];
#pragma unroll
    for (int a = 0; a < 4; ++a)
#pragma unroll
      for (int r = 0; r < 4; ++r) acc[a][r] += bv[a] * ui[r];
    __syncthreads();
#pragma unroll
    for (int r = 0; r < 4; ++r)
#pragma unroll
      for (int a = 0; a < 4; ++a)
        xs[(i_hi + 16 * r) * PAD + i_lo + 16 * a] = acc[a][r];
    __syncthreads();
#pragma unroll
    for (int r = 0; r < 4; ++r) {
      int id = TID + 256 * r;
      int bl = id >> 4, i0 = (id & 15) << 2;
      *reinterpret_cast<float4*>(&out[((size_t)t * 256 + b0 + bl) * 64 + i0]) =
          *reinterpret_cast<const float4*>(&xs[bl * PAD + i0]);
    }
  }
}

// ---------------- K3 (MFMA fp16 hi/lo) ----------------
__device__ __forceinline__ void gload_lds16(const void* g, void* l) {
  __builtin_amdgcn_global_load_lds(
      (const __attribute__((address_space(1))) unsigned int*)g,
      (__attribute__((address_space(3))) unsigned int*)l, 16, 0, 0);
}

constexpr int LDS_XH = 2 * SLOT;           // 40960
constexpr int LDS_XL = LDS_XH + 9216;      // 50176
constexpr int LDS_SZ = LDS_XL + 9216;      // 59392

__global__ __launch_bounds__(256) void k3_mfma(const unsigned char* __restrict__ Aws,
                                               const float* __restrict__ Hw,
                                               float* __restrict__ out) {
  __shared__ __align__(16) unsigned char sm[LDS_SZ];
  const int blk = blockIdx.x;
  // XCD swizzle: the 4 batch-group blocks of one superchunk land 8 apart -> same XCD L2
  const int s = (blk & 7) | ((blk >> 5) << 3);
  const int g = (blk >> 3) & 3;
  const int b0 = g << 6;
  const int lane = TID & 63, wave = TID >> 6;
  const int lm = lane & 15, quad = lane >> 4;
  const int wm = wave >> 1, wn = wave & 1;   // 2x2 wave grid over (i, b)

  // init X (fp16 hi/lo, [b][j] pitch 144 B) from Hw fp32
#pragma unroll
  for (int r = 0; r < 4; ++r) {
    int id = TID + (r << 8);
    int bl = id >> 4, j0 = (id & 15) << 2;
    float4 v = *reinterpret_cast<const float4*>(
        &Hw[(size_t)s * 16384 + (size_t)(b0 + bl) * 64 + j0]);
    float vv[4] = {v.x, v.y, v.z, v.w};
    half4v hh, ll;
#pragma unroll
    for (int e = 0; e < 4; ++e) {
      _Float16 h = (_Float16)vv[e];
      hh[e] = h;
      ll[e] = (_Float16)(vv[e] - (float)h);
    }
    *reinterpret_cast<half4v*>(sm + LDS_XH + bl * APITCH + (j0 << 1)) = hh;
    *reinterpret_cast<half4v*>(sm + LDS_XL + bl * APITCH + (j0 << 1)) = ll;
  }

  const size_t t0 = (size_t)s * 64;
  {  // prefetch slot 0 -> buf 0
    const unsigned char* gsl = Aws + t0 * SLOT;
#pragma unroll
    for (int r = 0; r < 5; ++r) {
      int off = ((r << 2) + wave) << 10;
      gload_lds16(gsl + off + lane * 16, sm + off);
    }
  }

  // loop-invariant fragment offsets
  int aoff[2][2], xoffh[2][2], xoffl[2][2], woff[2][2];
#pragma unroll
  for (int mt = 0; mt < 2; ++mt)
#pragma unroll
    for (int kt = 0; kt < 2; ++kt)
      aoff[mt][kt] = ((wm << 5) + (mt << 4) + lm) * APITCH + (((kt << 5) + (quad << 3)) << 1);
#pragma unroll
  for (int nt = 0; nt < 2; ++nt)
#pragma unroll
    for (int kt = 0; kt < 2; ++kt) {
      int o = ((wn << 5) + (nt << 4) + lm) * APITCH + (((kt << 5) + (quad << 3)) << 1);
      xoffh[nt][kt] = LDS_XH + o;
      xoffl[nt][kt] = LDS_XL + o;
    }
#pragma unroll
  for (int nt = 0; nt < 2; ++nt)
#pragma unroll
    for (int mt = 0; mt < 2; ++mt)
      woff[nt][mt] = ((wn << 5) + (nt << 4) + lm) * APITCH +
                     (((wm << 5) + (mt << 4) + (quad << 2)) << 1);

  __syncthreads();  // drains vmcnt -> buf0 + X ready

  int cur = 0;
  for (int k = 0; k < 64; ++k) {
    const unsigned char* ab = sm + cur * SLOT;
    if (k < 63) {  // prefetch next slot into other buffer (drained at mid-barrier)
      const unsigned char* gsl = Aws + (t0 + k + 1) * SLOT;
      unsigned char* lb = sm + (cur ^ 1) * SLOT;
#pragma unroll
      for (int r = 0; r < 5; ++r) {
        int off = ((r << 2) + wave) << 10;
        gload_lds16(gsl + off + lane * 16, lb + off);
      }
    }
    half8 fa[2][2], fal[2][2], fxh[2][2], fxl[2][2];
#pragma unroll
    for (int mt = 0; mt < 2; ++mt)
#pragma unroll
      for (int kt = 0; kt < 2; ++kt) {
        fa[mt][kt]  = *reinterpret_cast<const half8*>(ab + aoff[mt][kt]);
        fal[mt][kt] = *reinterpret_cast<const half8*>(ab + AL_OFF + aoff[mt][kt]);
      }
#pragma unroll
    for (int nt = 0; nt < 2; ++nt)
#pragma unroll
      for (int kt = 0; kt < 2; ++kt) {
        fxh[nt][kt] = *reinterpret_cast<const half8*>(sm + xoffh[nt][kt]);
        fxl[nt][kt] = *reinterpret_cast<const half8*>(sm + xoffl[nt][kt]);
      }
    float4 bv[2];
#pragma unroll
    for (int mt = 0; mt < 2; ++mt)
      bv[mt] = *reinterpret_cast<const float4*>(
          ab + BV_OFF + (((wm << 5) + (mt << 4) + (quad << 2)) << 2));
    float uu[2];
#pragma unroll
    for (int nt = 0; nt < 2; ++nt)
      uu[nt] = *reinterpret_cast<const float*>(
          ab + U_OFF + ((b0 + (wn << 5) + (nt << 4) + lm) << 2));

    f32x4 acc[2][2] = {};
#pragma unroll
    for (int mt = 0; mt < 2; ++mt)
#pragma unroll
      for (int nt = 0; nt < 2; ++nt)
#pragma unroll
        for (int kt = 0; kt < 2; ++kt) {
          acc[mt][nt] = __builtin_amdgcn_mfma_f32_16x16x32_f16(fa[mt][kt],  fxh[nt][kt], acc[mt][nt], 0, 0, 0);
          acc[mt][nt] = __builtin_amdgcn_mfma_f32_16x16x32_f16(fal[mt][kt], fxh[nt][kt], acc[mt][nt], 0, 0, 0);
          acc[mt][nt] = __builtin_amdgcn_mfma_f32_16x16x32_f16(fa[mt][kt],  fxl[nt][kt], acc[mt][nt], 0, 0, 0);
        }
    // += Bv[i] * u[b]
#pragma unroll
    for (int mt = 0; mt < 2; ++mt) {
      const float* bp = reinterpret_cast<const float*>(&bv[mt]);
#pragma unroll
      for (int nt = 0; nt < 2; ++nt)
#pragma unroll
        for (int e = 0; e < 4; ++e) acc[mt][nt][e] += bp[e] * uu[nt];
    }
    __syncthreads();  // all X frag reads done before overwrite
#pragma unroll
    for (int mt = 0; mt < 2; ++mt)
#pragma unroll
      for (int nt = 0; nt < 2; ++nt) {
        half4v hh, ll;
#pragma unroll
        for (int e = 0; e < 4; ++e) {
          float x = acc[mt][nt][e];
          _Float16 h = (_Float16)x;
          hh[e] = h;
          ll[e] = (_Float16)(x - (float)h);
        }
        *reinterpret_cast<half4v*>(sm + LDS_XH + woff[nt][mt]) = hh;
        *reinterpret_cast<half4v*>(sm + LDS_XL + woff[nt][mt]) = ll;
        const int bglob = b0 + (wn << 5) + (nt << 4) + lm;
        const int irow = (wm << 5) + (mt << 4) + (quad << 2);
        *reinterpret_cast<float4*>(&out[(((t0 + k) << 8) + bglob) * 64 + irow]) =
            make_float4(acc[mt][nt][0], acc[mt][nt][1], acc[mt][nt][2], acc[mt][nt][3]);
      }
    __syncthreads();  // X writes visible; prefetch drained
    cur ^= 1;
  }
}

extern "C" void kernel_launch(void* const* d_in, const int* in_sizes, int n_in,
                              void* d_out, int out_size, void* d_ws, size_t ws_size,
                              hipStream_t stream) {
  const float* inputs = (const float*)d_in[0];  // (4096, 256)
  const float* Ag     = (const float*)d_in[1];  // (4096, 64, 64)
  const float* Bg     = (const float*)d_in[2];  // (4096, 64)
  float* out = (float*)d_out;                   // (4096, 256, 64)

  const bool use_mfma = ws_size >= AWS_BYTES + OLD_WS_FLOATS * 4;
  unsigned char* Aws = (unsigned char*)d_ws;
  float* ws = (float*)((char*)d_ws + (use_mfma ? AWS_BYTES : 0));
  float* W  = ws + WS_W;
  float* Qw = ws + WS_Q;
  float* Pw = ws + WS_P;
  float* Zw = ws + WS_Z;
  float* Hw = ws + WS_H;

  if (use_mfma) k0_prep<<<4096, 256, 0, stream>>>(Ag, Bg, inputs, Aws);
  k1_suffix<<<256, 256, 0, stream>>>(Ag, Bg, W, Qw);
  k1b_combine<<<64, 256, 0, stream>>>(Qw, W, Pw);
  k1c_zgemm<<<256, 256, 0, stream>>>(inputs, W, Zw);
  k2_carry<<<64, 256, 0, stream>>>(Pw, Zw, Hw);
  if (use_mfma)
    k3_mfma<<<256, 256, 0, stream>>>(Aws, Hw, out);
  else
    k3_final<<<256, 256, 0, stream>>>(Ag, Bg, inputs, Hw, out);
}